// Round 1
// baseline (2947.718 us; speedup 1.0000x reference)
//
#include <hip/hip_runtime.h>

#define D 128
#define EPSV 1e-5f

// ---------------------------------------------------------------------------
// 16-lane (within-row) butterfly reduction; 16 threads share one row, they are
// consecutive lanes of the same wave (16 | 64).
__device__ __forceinline__ void reduce16(float& a, float& b) {
#pragma unroll
  for (int w = 1; w < 16; w <<= 1) {
    a += __shfl_xor(a, w, 64);
    b += __shfl_xor(b, w, 64);
  }
}

// ---------------------------------------------------------------------------
// Kernel 1: acc[n][:] = target_feat[n][:] @ W_input   (acc == d_out)
__global__ __launch_bounds__(256) void k_input(
    const float* __restrict__ tfeat, const float* __restrict__ Wi,
    float* __restrict__ acc, int N) {
  __shared__ float Wbuf[64][132];
  __shared__ float xt[16][132];
  const int t = threadIdx.x;
  const int r = t >> 4, s = t & 15, j0 = s * 8;
  const int row = blockIdx.x * 16 + r;

  // stage x tile (16 rows x 128), coalesced float4
  for (int idx = t; idx < 16 * 32; idx += 256) {
    int rr = idx >> 5, c4 = idx & 31;
    int grow = blockIdx.x * 16 + rr;
    float4 v = make_float4(0.f, 0.f, 0.f, 0.f);
    if (grow < N) v = *(const float4*)(tfeat + (size_t)grow * D + c4 * 4);
    *(float4*)&xt[rr][c4 * 4] = v;
  }

  float a[8] = {0, 0, 0, 0, 0, 0, 0, 0};
  for (int kc = 0; kc < 2; ++kc) {
    __syncthreads();
#pragma unroll
    for (int idx = t; idx < 64 * 32; idx += 256) {
      int kk = idx >> 5, c4 = idx & 31;
      *(float4*)&Wbuf[kk][c4 * 4] =
          *(const float4*)(Wi + (size_t)(kc * 64 + kk) * D + c4 * 4);
    }
    __syncthreads();
#pragma unroll 8
    for (int kk = 0; kk < 64; ++kk) {
      float xv = xt[r][kc * 64 + kk];
      float4 w0 = *(const float4*)&Wbuf[kk][j0];
      float4 w1 = *(const float4*)&Wbuf[kk][j0 + 4];
      a[0] += xv * w0.x; a[1] += xv * w0.y; a[2] += xv * w0.z; a[3] += xv * w0.w;
      a[4] += xv * w1.x; a[5] += xv * w1.y; a[6] += xv * w1.z; a[7] += xv * w1.w;
    }
  }
  if (row < N) {
    *(float4*)(acc + (size_t)row * D + j0)     = make_float4(a[0], a[1], a[2], a[3]);
    *(float4*)(acc + (size_t)row * D + j0 + 4) = make_float4(a[4], a[5], a[6], a[7]);
  }
}

// ---------------------------------------------------------------------------
// Kernel 2: fused edge pipeline + atomic scatter into acc (== d_out)
__global__ __launch_bounds__(256) void k_edge(
    const float* __restrict__ cfeat,
    const float* __restrict__ cpose, const float* __restrict__ tpose,
    const float* __restrict__ Wrp, const float* __restrict__ brp,
    const float* __restrict__ Wc1, const float* __restrict__ gc1,
    const float* __restrict__ bc1, const float* __restrict__ Wc2,
    const int* __restrict__ hi, const int* __restrict__ wi,
    float* __restrict__ acc, int E) {
  __shared__ float Wbuf[64][132];
  __shared__ float xt[16][260];  // 256-wide concat input, padded
  __shared__ float yt[16][132];
  const int t = threadIdx.x;
  const int r = t >> 4, s = t & 15, j0 = s * 8;
  const int e = blockIdx.x * 16 + r;
  const bool valid = e < E;
  const int h = valid ? hi[e] : 0;
  const int w = valid ? wi[e] : 0;

  // Phase A: xt[r][0:128] = context_feat[h]; xt[r][128:256] = relu(dpose @ Wrp + brp)
  {
    const float4* src = (const float4*)(cfeat + (size_t)h * D);
    *(float4*)&xt[r][j0]     = src[s * 2];
    *(float4*)&xt[r][j0 + 4] = src[s * 2 + 1];
  }
  {
    float d0 = cpose[h * 4 + 0] - tpose[w * 4 + 0];
    float d1 = cpose[h * 4 + 1] - tpose[w * 4 + 1];
    float d2 = cpose[h * 4 + 2] - tpose[w * 4 + 2];
    float d3 = cpose[h * 4 + 3] - tpose[w * 4 + 3];
#pragma unroll
    for (int m = 0; m < 8; ++m) {
      int j = j0 + m;
      float v = brp[j] + d0 * Wrp[j] + d1 * Wrp[D + j] + d2 * Wrp[2 * D + j] +
                d3 * Wrp[3 * D + j];
      xt[r][D + j] = fmaxf(v, 0.f);
    }
  }

  // Phase B: y = GN(relu-free)(x @ Wc1); K=256 in 4 chunks of 64
  float a[8] = {0, 0, 0, 0, 0, 0, 0, 0};
  for (int kc = 0; kc < 4; ++kc) {
    __syncthreads();
#pragma unroll
    for (int idx = t; idx < 64 * 32; idx += 256) {
      int kk = idx >> 5, c4 = idx & 31;
      *(float4*)&Wbuf[kk][c4 * 4] =
          *(const float4*)(Wc1 + (size_t)(kc * 64 + kk) * D + c4 * 4);
    }
    __syncthreads();
#pragma unroll 8
    for (int kk = 0; kk < 64; ++kk) {
      float xv = xt[r][kc * 64 + kk];
      float4 w0 = *(const float4*)&Wbuf[kk][j0];
      float4 w1 = *(const float4*)&Wbuf[kk][j0 + 4];
      a[0] += xv * w0.x; a[1] += xv * w0.y; a[2] += xv * w0.z; a[3] += xv * w0.w;
      a[4] += xv * w1.x; a[5] += xv * w1.y; a[6] += xv * w1.z; a[7] += xv * w1.w;
    }
  }
  // GroupNorm(1) over 128 channels + relu -> yt
  {
    float s1 = 0.f, s2 = 0.f;
#pragma unroll
    for (int m = 0; m < 8; ++m) { s1 += a[m]; s2 += a[m] * a[m]; }
    reduce16(s1, s2);
    float mean = s1 * (1.f / 128.f);
    float var = s2 * (1.f / 128.f) - mean * mean;
    float rstd = rsqrtf(var + EPSV);
#pragma unroll
    for (int m = 0; m < 8; ++m) {
      int j = j0 + m;
      float v = (a[m] - mean) * rstd * gc1[j] + bc1[j];
      yt[r][j] = fmaxf(v, 0.f);
    }
  }

  // Phase C: z = y @ Wc2 ; scatter-add
  float a2[8] = {0, 0, 0, 0, 0, 0, 0, 0};
  for (int kc = 0; kc < 2; ++kc) {
    __syncthreads();
#pragma unroll
    for (int idx = t; idx < 64 * 32; idx += 256) {
      int kk = idx >> 5, c4 = idx & 31;
      *(float4*)&Wbuf[kk][c4 * 4] =
          *(const float4*)(Wc2 + (size_t)(kc * 64 + kk) * D + c4 * 4);
    }
    __syncthreads();
#pragma unroll 8
    for (int kk = 0; kk < 64; ++kk) {
      float yv = yt[r][kc * 64 + kk];
      float4 w0 = *(const float4*)&Wbuf[kk][j0];
      float4 w1 = *(const float4*)&Wbuf[kk][j0 + 4];
      a2[0] += yv * w0.x; a2[1] += yv * w0.y; a2[2] += yv * w0.z; a2[3] += yv * w0.w;
      a2[4] += yv * w1.x; a2[5] += yv * w1.y; a2[6] += yv * w1.z; a2[7] += yv * w1.w;
    }
  }
  if (valid) {
    float* dst = acc + (size_t)w * D + j0;
#pragma unroll
    for (int m = 0; m < 8; ++m) unsafeAtomicAdd(dst + m, a2[m]);
  }
}

// ---------------------------------------------------------------------------
// Kernel 3: node pipeline, in-place on acc (== d_out):
// t = relu(GN(acc)); t = relu(GN(t@Wm1)); t = GN(t@Wm2); out = relu(t + tfeat)
__global__ __launch_bounds__(256) void k_node(
    const float* __restrict__ tfeat,
    const float* __restrict__ gn, const float* __restrict__ bn,
    const float* __restrict__ Wm1, const float* __restrict__ gm1,
    const float* __restrict__ bm1,
    const float* __restrict__ Wm2, const float* __restrict__ gm2,
    const float* __restrict__ bm2,
    float* __restrict__ acc, int N) {
  __shared__ float Wbuf[64][132];
  __shared__ float xt[16][132];
  __shared__ float yt[16][132];
  const int t = threadIdx.x;
  const int r = t >> 4, s = t & 15, j0 = s * 8;
  const int row = blockIdx.x * 16 + r;
  const bool valid = row < N;

  // Stage 1: GN(acc)+relu -> xt
  float v[8] = {0, 0, 0, 0, 0, 0, 0, 0};
  if (valid) {
    float4 v0 = *(const float4*)(acc + (size_t)row * D + j0);
    float4 v1 = *(const float4*)(acc + (size_t)row * D + j0 + 4);
    v[0] = v0.x; v[1] = v0.y; v[2] = v0.z; v[3] = v0.w;
    v[4] = v1.x; v[5] = v1.y; v[6] = v1.z; v[7] = v1.w;
  }
  {
    float s1 = 0.f, s2 = 0.f;
#pragma unroll
    for (int m = 0; m < 8; ++m) { s1 += v[m]; s2 += v[m] * v[m]; }
    reduce16(s1, s2);
    float mean = s1 * (1.f / 128.f);
    float var = s2 * (1.f / 128.f) - mean * mean;
    float rstd = rsqrtf(var + EPSV);
#pragma unroll
    for (int m = 0; m < 8; ++m) {
      int j = j0 + m;
      float x = (v[m] - mean) * rstd * gn[j] + bn[j];
      xt[r][j] = fmaxf(x, 0.f);
    }
  }

  // Stage 2: a = xt @ Wm1 ; GN + relu -> yt
  float a[8] = {0, 0, 0, 0, 0, 0, 0, 0};
  for (int kc = 0; kc < 2; ++kc) {
    __syncthreads();
#pragma unroll
    for (int idx = t; idx < 64 * 32; idx += 256) {
      int kk = idx >> 5, c4 = idx & 31;
      *(float4*)&Wbuf[kk][c4 * 4] =
          *(const float4*)(Wm1 + (size_t)(kc * 64 + kk) * D + c4 * 4);
    }
    __syncthreads();
#pragma unroll 8
    for (int kk = 0; kk < 64; ++kk) {
      float xv = xt[r][kc * 64 + kk];
      float4 w0 = *(const float4*)&Wbuf[kk][j0];
      float4 w1 = *(const float4*)&Wbuf[kk][j0 + 4];
      a[0] += xv * w0.x; a[1] += xv * w0.y; a[2] += xv * w0.z; a[3] += xv * w0.w;
      a[4] += xv * w1.x; a[5] += xv * w1.y; a[6] += xv * w1.z; a[7] += xv * w1.w;
    }
  }
  {
    float s1 = 0.f, s2 = 0.f;
#pragma unroll
    for (int m = 0; m < 8; ++m) { s1 += a[m]; s2 += a[m] * a[m]; }
    reduce16(s1, s2);
    float mean = s1 * (1.f / 128.f);
    float var = s2 * (1.f / 128.f) - mean * mean;
    float rstd = rsqrtf(var + EPSV);
#pragma unroll
    for (int m = 0; m < 8; ++m) {
      int j = j0 + m;
      float x = (a[m] - mean) * rstd * gm1[j] + bm1[j];
      yt[r][j] = fmaxf(x, 0.f);
    }
  }

  // Stage 3: a2 = yt @ Wm2 ; GN ; residual + relu -> acc (out)
  float a2[8] = {0, 0, 0, 0, 0, 0, 0, 0};
  for (int kc = 0; kc < 2; ++kc) {
    __syncthreads();
#pragma unroll
    for (int idx = t; idx < 64 * 32; idx += 256) {
      int kk = idx >> 5, c4 = idx & 31;
      *(float4*)&Wbuf[kk][c4 * 4] =
          *(const float4*)(Wm2 + (size_t)(kc * 64 + kk) * D + c4 * 4);
    }
    __syncthreads();
#pragma unroll 8
    for (int kk = 0; kk < 64; ++kk) {
      float yv = yt[r][kc * 64 + kk];
      float4 w0 = *(const float4*)&Wbuf[kk][j0];
      float4 w1 = *(const float4*)&Wbuf[kk][j0 + 4];
      a2[0] += yv * w0.x; a2[1] += yv * w0.y; a2[2] += yv * w0.z; a2[3] += yv * w0.w;
      a2[4] += yv * w1.x; a2[5] += yv * w1.y; a2[6] += yv * w1.z; a2[7] += yv * w1.w;
    }
  }
  {
    float s1 = 0.f, s2 = 0.f;
#pragma unroll
    for (int m = 0; m < 8; ++m) { s1 += a2[m]; s2 += a2[m] * a2[m]; }
    reduce16(s1, s2);
    float mean = s1 * (1.f / 128.f);
    float var = s2 * (1.f / 128.f) - mean * mean;
    float rstd = rsqrtf(var + EPSV);
    if (valid) {
      float o[8];
#pragma unroll
      for (int m = 0; m < 8; ++m) {
        int j = j0 + m;
        float x = (a2[m] - mean) * rstd * gm2[j] + bm2[j];
        o[m] = fmaxf(x + tfeat[(size_t)row * D + j], 0.f);
      }
      *(float4*)(acc + (size_t)row * D + j0)     = make_float4(o[0], o[1], o[2], o[3]);
      *(float4*)(acc + (size_t)row * D + j0 + 4) = make_float4(o[4], o[5], o[6], o[7]);
    }
  }
}

// ---------------------------------------------------------------------------
extern "C" void kernel_launch(void* const* d_in, const int* in_sizes, int n_in,
                              void* d_out, int out_size, void* d_ws,
                              size_t ws_size, hipStream_t stream) {
  const float* cfeat = (const float*)d_in[0];
  const float* tfeat = (const float*)d_in[1];
  const float* cpose = (const float*)d_in[2];
  const float* tpose = (const float*)d_in[3];
  const float* Wi    = (const float*)d_in[4];
  const float* Wrp   = (const float*)d_in[5];
  const float* brp   = (const float*)d_in[6];
  const float* Wc1   = (const float*)d_in[7];
  const float* gc1   = (const float*)d_in[8];
  const float* bc1   = (const float*)d_in[9];
  const float* Wc2   = (const float*)d_in[10];
  const float* gn    = (const float*)d_in[11];
  const float* bn    = (const float*)d_in[12];
  const float* Wm1   = (const float*)d_in[13];
  const float* gm1   = (const float*)d_in[14];
  const float* bm1   = (const float*)d_in[15];
  const float* Wm2   = (const float*)d_in[16];
  const float* gm2   = (const float*)d_in[17];
  const float* bm2   = (const float*)d_in[18];
  const int* hi      = (const int*)d_in[19];
  const int* wi      = (const int*)d_in[20];

  const int N = in_sizes[1] / D;   // 40000 targets
  const int E = in_sizes[19];      // 640000 edges
  float* out = (float*)d_out;      // doubles as the f32 accumulator

  const int nbN = (N + 15) / 16;
  const int nbE = (E + 15) / 16;

  k_input<<<nbN, 256, 0, stream>>>(tfeat, Wi, out, N);
  k_edge<<<nbE, 256, 0, stream>>>(cfeat, cpose, tpose, Wrp, brp, Wc1, gc1, bc1,
                                  Wc2, hi, wi, out, E);
  k_node<<<nbN, 256, 0, stream>>>(tfeat, gn, bn, Wm1, gm1, bm1, Wm2, gm2, bm2,
                                  out, N);
}

// Round 2
// 569.299 us; speedup vs baseline: 5.1778x; 5.1778x over previous
//
#include <hip/hip_runtime.h>

#define D 128
#define EPSV 1e-5f

typedef __attribute__((ext_vector_type(8))) __bf16 bf16x8;
typedef __attribute__((ext_vector_type(4))) float f32x4;

__device__ __forceinline__ ushort f2bf(float x) {
  unsigned u = __float_as_uint(x);
  u += 0x7fffu + ((u >> 16) & 1u);
  return (ushort)(u >> 16);
}
__device__ __forceinline__ unsigned pk2(float a, float b) {
  return (unsigned)f2bf(a) | ((unsigned)f2bf(b) << 16);
}

// ---------------------------------------------------------------------------
// Convert Wc1 (256x128 f32) -> WT1 (128x256 bf16, transposed) and
//         Wc2 (128x128 f32) -> WT2 (128x128 bf16, transposed) in d_ws.
__global__ void k_cvt(const float* __restrict__ Wc1, const float* __restrict__ Wc2,
                      ushort* __restrict__ WT1, ushort* __restrict__ WT2) {
  int i = blockIdx.x * 256 + threadIdx.x;
  if (i < 128 * 256) {
    int n = i >> 8, k = i & 255;
    WT1[i] = f2bf(Wc1[k * 128 + n]);
  } else {
    int j = i - 128 * 256;
    if (j < 128 * 128) {
      int n = j >> 7, k = j & 127;
      WT2[j] = f2bf(Wc2[k * 128 + n]);
    }
  }
}

// ---------------------------------------------------------------------------
// MFMA edge kernel: 64 edges/block, 4 waves, wave w -> edges [w*16, w*16+16).
// GEMM1: X[64x256] @ Wc1 -> GN+relu -> Y[64x128] -> GEMM2: Y @ Wc2 -> scatter.
__global__ __launch_bounds__(256, 3) void k_edge(
    const float* __restrict__ cfeat,
    const float* __restrict__ cpose, const float* __restrict__ tpose,
    const float* __restrict__ Wrp, const float* __restrict__ brp,
    const float* __restrict__ gc1, const float* __restrict__ bc1,
    const ushort* __restrict__ WT1, const ushort* __restrict__ WT2,
    const int* __restrict__ hi, const int* __restrict__ wi,
    float* __restrict__ acc, int E) {
  // Wbuf: [buf][g*1024 + col*8 + j] bf16, one K=32 chunk of W^T (all 128 cols)
  __shared__ ushort Wbuf[2][4096];
  // XY: Xl rows stride 264 (256+8 pad) during GEMM1; reused as Yl stride 136.
  __shared__ ushort XY[64 * 264];
  __shared__ int wl[64];

  const int t = threadIdx.x;
  const int e0 = blockIdx.x * 64;

  // ---- stage hi/wi + gather X + relpose (phase 0) ----
  {
    if (t < 64) wl[t] = wi[min(e0 + t, E - 1)];
    const int e = t >> 2, q = t & 3;  // 4 threads per edge, 32 cols each
    const int ge = min(e0 + e, E - 1);
    const int h = hi[ge];
    const int w = wi[ge];
    ushort* xrow = &XY[e * 264];
    // gather context_feat[h] -> bf16
    const float4* src = (const float4*)(cfeat + (size_t)h * D + q * 32);
#pragma unroll
    for (int c = 0; c < 4; ++c) {
      float4 f0 = src[c * 2], f1 = src[c * 2 + 1];
      uint4 pk;
      pk.x = pk2(f0.x, f0.y); pk.y = pk2(f0.z, f0.w);
      pk.z = pk2(f1.x, f1.y); pk.w = pk2(f1.z, f1.w);
      *(uint4*)&xrow[q * 32 + c * 8] = pk;
    }
    // relpose: relu((cpose[h]-tpose[w]) @ Wrp + brp), cols q*32..q*32+32
    float4 cp = *(const float4*)(cpose + (size_t)h * 4);
    float4 tp = *(const float4*)(tpose + (size_t)w * 4);
    const float dd[4] = {cp.x - tp.x, cp.y - tp.y, cp.z - tp.z, cp.w - tp.w};
#pragma unroll
    for (int c = 0; c < 4; ++c) {
      const int j = q * 32 + c * 8;
      float v[8];
      float4 b0 = *(const float4*)(brp + j);
      float4 b1 = *(const float4*)(brp + j + 4);
      v[0] = b0.x; v[1] = b0.y; v[2] = b0.z; v[3] = b0.w;
      v[4] = b1.x; v[5] = b1.y; v[6] = b1.z; v[7] = b1.w;
#pragma unroll
      for (int i = 0; i < 4; ++i) {
        float4 w0 = *(const float4*)(Wrp + i * D + j);
        float4 w1 = *(const float4*)(Wrp + i * D + j + 4);
        v[0] += dd[i] * w0.x; v[1] += dd[i] * w0.y;
        v[2] += dd[i] * w0.z; v[3] += dd[i] * w0.w;
        v[4] += dd[i] * w1.x; v[5] += dd[i] * w1.y;
        v[6] += dd[i] * w1.z; v[7] += dd[i] * w1.w;
      }
      uint4 pk;
      pk.x = pk2(fmaxf(v[0], 0.f), fmaxf(v[1], 0.f));
      pk.y = pk2(fmaxf(v[2], 0.f), fmaxf(v[3], 0.f));
      pk.z = pk2(fmaxf(v[4], 0.f), fmaxf(v[5], 0.f));
      pk.w = pk2(fmaxf(v[6], 0.f), fmaxf(v[7], 0.f));
      *(uint4*)&xrow[D + j] = pk;
    }
  }

  // ---- stage W chunk helper: global chunk c (0..11) -> Wbuf[nb] ----
  auto stage = [&](int c, int nb) {
    const ushort* Wt = (c < 8) ? WT1 : WT2;
    const int koff = (c < 8 ? c : c - 8) * 32;
    const int krow = (c < 8) ? 256 : 128;
    const int col = t & 127;
    const int g0 = t >> 7;
#pragma unroll
    for (int v = 0; v < 2; ++v) {
      const int g = g0 + v * 2;
      uint4 d = *(const uint4*)(Wt + (size_t)col * krow + koff + g * 8);
      *(uint4*)&Wbuf[nb][(g * 128 + col) * 8] = d;
    }
  };

  stage(0, 0);
  __syncthreads();

  const int lane = t & 63;
  const int wv = t >> 6;
  const int r0 = wv * 16;            // wave's edge-row base
  const int s = lane & 15;           // col-in-tile / A-row lane
  const int g = lane >> 4;           // K-group

  // ---- GEMM1: K=256, 8 chunks ----
  f32x4 acc1[8];
#pragma unroll
  for (int ct = 0; ct < 8; ++ct) acc1[ct] = (f32x4){0.f, 0.f, 0.f, 0.f};

  for (int kc = 0; kc < 8; ++kc) {
    const int nb = kc & 1;
    stage(kc + 1, nb ^ 1);
    bf16x8 a = *(const bf16x8*)&XY[(r0 + s) * 264 + kc * 32 + g * 8];
#pragma unroll
    for (int ct = 0; ct < 8; ++ct) {
      bf16x8 b = *(const bf16x8*)&Wbuf[nb][g * 1024 + (ct * 16 + s) * 8];
      acc1[ct] = __builtin_amdgcn_mfma_f32_16x16x32_bf16(a, b, acc1[ct], 0, 0, 0);
    }
    __syncthreads();
  }

  // ---- GroupNorm(128) + relu -> Yl (bf16, stride 136), in-wave stats ----
  {
    float gcv[8], bcv[8];
#pragma unroll
    for (int ct = 0; ct < 8; ++ct) {
      gcv[ct] = gc1[ct * 16 + s];
      bcv[ct] = bc1[ct * 16 + s];
    }
    float p1[4], p2[4];
#pragma unroll
    for (int reg = 0; reg < 4; ++reg) {
      float s1 = 0.f, s2 = 0.f;
#pragma unroll
      for (int ct = 0; ct < 8; ++ct) {
        float v = acc1[ct][reg];
        s1 += v; s2 += v * v;
      }
#pragma unroll
      for (int m = 1; m < 16; m <<= 1) {
        s1 += __shfl_xor(s1, m, 64);
        s2 += __shfl_xor(s2, m, 64);
      }
      p1[reg] = s1; p2[reg] = s2;
    }
#pragma unroll
    for (int reg = 0; reg < 4; ++reg) {
      const float mean = p1[reg] * (1.f / 128.f);
      const float var = p2[reg] * (1.f / 128.f) - mean * mean;
      const float rstd = rsqrtf(var + EPSV);
      const int row = r0 + g * 4 + reg;
#pragma unroll
      for (int ct = 0; ct < 8; ++ct) {
        float y = (acc1[ct][reg] - mean) * rstd * gcv[ct] + bcv[ct];
        XY[row * 136 + ct * 16 + s] = f2bf(fmaxf(y, 0.f));
      }
    }
  }

  // ---- GEMM2: K=128, 4 chunks (global chunks 8..11) ----
  f32x4 acc2[8];
#pragma unroll
  for (int ct = 0; ct < 8; ++ct) acc2[ct] = (f32x4){0.f, 0.f, 0.f, 0.f};

  for (int kc = 0; kc < 4; ++kc) {
    const int c = 8 + kc;
    const int nb = c & 1;
    if (c < 11) stage(c + 1, nb ^ 1);
    bf16x8 a = *(const bf16x8*)&XY[(r0 + s) * 136 + kc * 32 + g * 8];
#pragma unroll
    for (int ct = 0; ct < 8; ++ct) {
      bf16x8 b = *(const bf16x8*)&Wbuf[nb][g * 1024 + (ct * 16 + s) * 8];
      acc2[ct] = __builtin_amdgcn_mfma_f32_16x16x32_bf16(a, b, acc2[ct], 0, 0, 0);
    }
    __syncthreads();
  }

  // ---- scatter-add ----
#pragma unroll
  for (int reg = 0; reg < 4; ++reg) {
    const int e_loc = r0 + g * 4 + reg;
    if (e0 + e_loc < E) {
      const int w = wl[e_loc];
      float* base = acc + (size_t)w * D + s;
#pragma unroll
      for (int ct = 0; ct < 8; ++ct)
        unsafeAtomicAdd(base + ct * 16, acc2[ct][reg]);
    }
  }
}

// ---------------------------------------------------------------------------
// 16-lane butterfly reduction (f32 VALU kernels below)
__device__ __forceinline__ void reduce16(float& a, float& b) {
#pragma unroll
  for (int w = 1; w < 16; w <<= 1) {
    a += __shfl_xor(a, w, 64);
    b += __shfl_xor(b, w, 64);
  }
}

// ---------------------------------------------------------------------------
// Kernel 1: acc[n][:] = target_feat[n][:] @ W_input   (acc == d_out)
__global__ __launch_bounds__(256) void k_input(
    const float* __restrict__ tfeat, const float* __restrict__ Wi,
    float* __restrict__ acc, int N) {
  __shared__ float Wbuf[64][132];
  __shared__ float xt[16][132];
  const int t = threadIdx.x;
  const int r = t >> 4, s = t & 15, j0 = s * 8;
  const int row = blockIdx.x * 16 + r;

  for (int idx = t; idx < 16 * 32; idx += 256) {
    int rr = idx >> 5, c4 = idx & 31;
    int grow = blockIdx.x * 16 + rr;
    float4 v = make_float4(0.f, 0.f, 0.f, 0.f);
    if (grow < N) v = *(const float4*)(tfeat + (size_t)grow * D + c4 * 4);
    *(float4*)&xt[rr][c4 * 4] = v;
  }

  float a[8] = {0, 0, 0, 0, 0, 0, 0, 0};
  for (int kc = 0; kc < 2; ++kc) {
    __syncthreads();
#pragma unroll
    for (int idx = t; idx < 64 * 32; idx += 256) {
      int kk = idx >> 5, c4 = idx & 31;
      *(float4*)&Wbuf[kk][c4 * 4] =
          *(const float4*)(Wi + (size_t)(kc * 64 + kk) * D + c4 * 4);
    }
    __syncthreads();
#pragma unroll 8
    for (int kk = 0; kk < 64; ++kk) {
      float xv = xt[r][kc * 64 + kk];
      float4 w0 = *(const float4*)&Wbuf[kk][j0];
      float4 w1 = *(const float4*)&Wbuf[kk][j0 + 4];
      a[0] += xv * w0.x; a[1] += xv * w0.y; a[2] += xv * w0.z; a[3] += xv * w0.w;
      a[4] += xv * w1.x; a[5] += xv * w1.y; a[6] += xv * w1.z; a[7] += xv * w1.w;
    }
  }
  if (row < N) {
    *(float4*)(acc + (size_t)row * D + j0)     = make_float4(a[0], a[1], a[2], a[3]);
    *(float4*)(acc + (size_t)row * D + j0 + 4) = make_float4(a[4], a[5], a[6], a[7]);
  }
}

// ---------------------------------------------------------------------------
// Kernel 3: node pipeline, in-place on acc (== d_out)
__global__ __launch_bounds__(256) void k_node(
    const float* __restrict__ tfeat,
    const float* __restrict__ gn, const float* __restrict__ bn,
    const float* __restrict__ Wm1, const float* __restrict__ gm1,
    const float* __restrict__ bm1,
    const float* __restrict__ Wm2, const float* __restrict__ gm2,
    const float* __restrict__ bm2,
    float* __restrict__ acc, int N) {
  __shared__ float Wbuf[64][132];
  __shared__ float xt[16][132];
  __shared__ float yt[16][132];
  const int t = threadIdx.x;
  const int r = t >> 4, s = t & 15, j0 = s * 8;
  const int row = blockIdx.x * 16 + r;
  const bool valid = row < N;

  float v[8] = {0, 0, 0, 0, 0, 0, 0, 0};
  if (valid) {
    float4 v0 = *(const float4*)(acc + (size_t)row * D + j0);
    float4 v1 = *(const float4*)(acc + (size_t)row * D + j0 + 4);
    v[0] = v0.x; v[1] = v0.y; v[2] = v0.z; v[3] = v0.w;
    v[4] = v1.x; v[5] = v1.y; v[6] = v1.z; v[7] = v1.w;
  }
  {
    float s1 = 0.f, s2 = 0.f;
#pragma unroll
    for (int m = 0; m < 8; ++m) { s1 += v[m]; s2 += v[m] * v[m]; }
    reduce16(s1, s2);
    float mean = s1 * (1.f / 128.f);
    float var = s2 * (1.f / 128.f) - mean * mean;
    float rstd = rsqrtf(var + EPSV);
#pragma unroll
    for (int m = 0; m < 8; ++m) {
      int j = j0 + m;
      float x = (v[m] - mean) * rstd * gn[j] + bn[j];
      xt[r][j] = fmaxf(x, 0.f);
    }
  }

  float a[8] = {0, 0, 0, 0, 0, 0, 0, 0};
  for (int kc = 0; kc < 2; ++kc) {
    __syncthreads();
#pragma unroll
    for (int idx = t; idx < 64 * 32; idx += 256) {
      int kk = idx >> 5, c4 = idx & 31;
      *(float4*)&Wbuf[kk][c4 * 4] =
          *(const float4*)(Wm1 + (size_t)(kc * 64 + kk) * D + c4 * 4);
    }
    __syncthreads();
#pragma unroll 8
    for (int kk = 0; kk < 64; ++kk) {
      float xv = xt[r][kc * 64 + kk];
      float4 w0 = *(const float4*)&Wbuf[kk][j0];
      float4 w1 = *(const float4*)&Wbuf[kk][j0 + 4];
      a[0] += xv * w0.x; a[1] += xv * w0.y; a[2] += xv * w0.z; a[3] += xv * w0.w;
      a[4] += xv * w1.x; a[5] += xv * w1.y; a[6] += xv * w1.z; a[7] += xv * w1.w;
    }
  }
  {
    float s1 = 0.f, s2 = 0.f;
#pragma unroll
    for (int m = 0; m < 8; ++m) { s1 += a[m]; s2 += a[m] * a[m]; }
    reduce16(s1, s2);
    float mean = s1 * (1.f / 128.f);
    float var = s2 * (1.f / 128.f) - mean * mean;
    float rstd = rsqrtf(var + EPSV);
#pragma unroll
    for (int m = 0; m < 8; ++m) {
      int j = j0 + m;
      float x = (a[m] - mean) * rstd * gm1[j] + bm1[j];
      yt[r][j] = fmaxf(x, 0.f);
    }
  }

  float a2[8] = {0, 0, 0, 0, 0, 0, 0, 0};
  for (int kc = 0; kc < 2; ++kc) {
    __syncthreads();
#pragma unroll
    for (int idx = t; idx < 64 * 32; idx += 256) {
      int kk = idx >> 5, c4 = idx & 31;
      *(float4*)&Wbuf[kk][c4 * 4] =
          *(const float4*)(Wm2 + (size_t)(kc * 64 + kk) * D + c4 * 4);
    }
    __syncthreads();
#pragma unroll 8
    for (int kk = 0; kk < 64; ++kk) {
      float yv = yt[r][kc * 64 + kk];
      float4 w0 = *(const float4*)&Wbuf[kk][j0];
      float4 w1 = *(const float4*)&Wbuf[kk][j0 + 4];
      a2[0] += yv * w0.x; a2[1] += yv * w0.y; a2[2] += yv * w0.z; a2[3] += yv * w0.w;
      a2[4] += yv * w1.x; a2[5] += yv * w1.y; a2[6] += yv * w1.z; a2[7] += yv * w1.w;
    }
  }
  {
    float s1 = 0.f, s2 = 0.f;
#pragma unroll
    for (int m = 0; m < 8; ++m) { s1 += a2[m]; s2 += a2[m] * a2[m]; }
    reduce16(s1, s2);
    float mean = s1 * (1.f / 128.f);
    float var = s2 * (1.f / 128.f) - mean * mean;
    float rstd = rsqrtf(var + EPSV);
    if (valid) {
      float o[8];
#pragma unroll
      for (int m = 0; m < 8; ++m) {
        int j = j0 + m;
        float x = (a2[m] - mean) * rstd * gm2[j] + bm2[j];
        o[m] = fmaxf(x + tfeat[(size_t)row * D + j], 0.f);
      }
      *(float4*)(acc + (size_t)row * D + j0)     = make_float4(o[0], o[1], o[2], o[3]);
      *(float4*)(acc + (size_t)row * D + j0 + 4) = make_float4(o[4], o[5], o[6], o[7]);
    }
  }
}

// ---------------------------------------------------------------------------
extern "C" void kernel_launch(void* const* d_in, const int* in_sizes, int n_in,
                              void* d_out, int out_size, void* d_ws,
                              size_t ws_size, hipStream_t stream) {
  const float* cfeat = (const float*)d_in[0];
  const float* tfeat = (const float*)d_in[1];
  const float* cpose = (const float*)d_in[2];
  const float* tpose = (const float*)d_in[3];
  const float* Wi    = (const float*)d_in[4];
  const float* Wrp   = (const float*)d_in[5];
  const float* brp   = (const float*)d_in[6];
  const float* Wc1   = (const float*)d_in[7];
  const float* gc1   = (const float*)d_in[8];
  const float* bc1   = (const float*)d_in[9];
  const float* Wc2   = (const float*)d_in[10];
  const float* gn    = (const float*)d_in[11];
  const float* bn    = (const float*)d_in[12];
  const float* Wm1   = (const float*)d_in[13];
  const float* gm1   = (const float*)d_in[14];
  const float* bm1   = (const float*)d_in[15];
  const float* Wm2   = (const float*)d_in[16];
  const float* gm2   = (const float*)d_in[17];
  const float* bm2   = (const float*)d_in[18];
  const int* hi      = (const int*)d_in[19];
  const int* wi      = (const int*)d_in[20];

  const int N = in_sizes[1] / D;   // 40000 targets
  const int E = in_sizes[19];      // 640000 edges
  float* out = (float*)d_out;      // doubles as the f32 accumulator

  ushort* WT1 = (ushort*)d_ws;          // 128x256 bf16 (Wc1^T)
  ushort* WT2 = WT1 + 128 * 256;        // 128x128 bf16 (Wc2^T)

  const int nbN = (N + 15) / 16;
  const int nbE = (E + 63) / 64;

  k_cvt<<<192, 256, 0, stream>>>(Wc1, Wc2, WT1, WT2);
  k_input<<<nbN, 256, 0, stream>>>(tfeat, Wi, out, N);
  k_edge<<<nbE, 256, 0, stream>>>(cfeat, cpose, tpose, Wrp, brp, gc1, bc1,
                                  WT1, WT2, hi, wi, out, E);
  k_node<<<nbN, 256, 0, stream>>>(tfeat, gn, bn, Wm1, gm1, bm1, Wm2, gm2, bm2,
                                  out, N);
}

// Round 3
// 457.492 us; speedup vs baseline: 6.4432x; 1.2444x over previous
//
#include <hip/hip_runtime.h>

#define D 128
#define EPSV 1e-5f

typedef __attribute__((ext_vector_type(8))) __bf16 bf16x8;
typedef __attribute__((ext_vector_type(4))) float f32x4;

__device__ __forceinline__ ushort f2bf(float x) {
  unsigned u = __float_as_uint(x);
  u += 0x7fffu + ((u >> 16) & 1u);
  return (ushort)(u >> 16);
}
__device__ __forceinline__ unsigned pk2(float a, float b) {
  return (unsigned)f2bf(a) | ((unsigned)f2bf(b) << 16);
}

// ---------------------------------------------------------------------------
// Wc1 (256x128 f32) -> WT1 (128x256 bf16 transposed); Wc2 -> WT2 (128x128).
__global__ void k_cvt(const float* __restrict__ Wc1, const float* __restrict__ Wc2,
                      ushort* __restrict__ WT1, ushort* __restrict__ WT2) {
  int i = blockIdx.x * 256 + threadIdx.x;
  if (i < 128 * 256) {
    int n = i >> 8, k = i & 255;
    WT1[i] = f2bf(Wc1[k * 128 + n]);
  } else {
    int j = i - 128 * 256;
    if (j < 128 * 128) {
      int n = j >> 7, k = j & 127;
      WT2[j] = f2bf(Wc2[k * 128 + n]);
    }
  }
}

// ---------------------------------------------------------------------------
// k_edge v3: 128 edges/block, 4 waves in 2x2 grid, each wave 64 rows x 64 cols
// (4x4 grid of 16x16 MFMA tiles). A (cfeat half) gathered直接 from global;
// relpose half + Y staged in LDS; W double-buffered via global_load_lds.
__global__ __launch_bounds__(256, 3) void k_edge(
    const float* __restrict__ cfeat,
    const float* __restrict__ cpose, const float* __restrict__ tpose,
    const float* __restrict__ Wrp, const float* __restrict__ brp,
    const float* __restrict__ gc1, const float* __restrict__ bc1,
    const ushort* __restrict__ WT1, const ushort* __restrict__ WT2,
    const int* __restrict__ hi, const int* __restrict__ wi,
    float* __restrict__ acc, int E) {
  __shared__ ushort Wbuf[2][4096];      // 2 x 8KB: one K=32 chunk, 128 cols
  __shared__ ushort Ybuf[128 * 136];    // relpose X2, then Y (stride 272B)
  __shared__ float gnbuf[2][128][2];    // per-row (sum, sumsq) per col-half
  __shared__ int wl[128];

  const int t = threadIdx.x;
  const int lane = t & 63;
  const int wv = t >> 6;
  const int wm = wv >> 1, wn = wv & 1;  // wave's M-half / N-half
  const int s = lane & 15, g = lane >> 4;
  const int e0 = blockIdx.x * 128;

  // W chunk c (0..7 = WT1 K-chunks, 8..11 = WT2) -> Wbuf[nb], async to LDS.
  auto stage = [&](int c, int nb) {
    const ushort* Wt = (c < 8) ? WT1 : WT2;
    const int koff = (c < 8 ? c : c - 8) * 32;
    const int krow = (c < 8) ? 256 : 128;
    const int col = t & 127, g0 = t >> 7;
#pragma unroll
    for (int v = 0; v < 2; ++v) {
      const int gg = g0 + v * 2;
      const ushort* src = Wt + (size_t)col * krow + koff + gg * 8;
      ushort* dst = &Wbuf[nb][(gg * 128 + col) * 8];
      __builtin_amdgcn_global_load_lds(
          (const __attribute__((address_space(1))) void*)src,
          (__attribute__((address_space(3))) void*)dst, 16, 0, 0);
    }
  };

  stage(0, 0);
  if (t < 128) wl[t] = wi[min(e0 + t, E - 1)];

  int hl[4];
#pragma unroll
  for (int m = 0; m < 4; ++m)
    hl[m] = hi[min(e0 + wm * 64 + m * 16 + s, E - 1)];

  // relpose: edge e = t>>1, col half (t&1)*64 -> Ybuf (bf16)
  {
    const int e = t >> 1;
    const int jh = (t & 1) * 64;
    const int ge = min(e0 + e, E - 1);
    const int h = hi[ge], w = wi[ge];
    float4 cp = *(const float4*)(cpose + (size_t)h * 4);
    float4 tp = *(const float4*)(tpose + (size_t)w * 4);
    const float d0 = cp.x - tp.x, d1 = cp.y - tp.y;
    const float d2 = cp.z - tp.z, d3 = cp.w - tp.w;
#pragma unroll
    for (int q = 0; q < 16; ++q) {
      const int j = jh + q * 4;
      float4 b  = *(const float4*)(brp + j);
      float4 w0 = *(const float4*)(Wrp + j);
      float4 w1 = *(const float4*)(Wrp + D + j);
      float4 w2 = *(const float4*)(Wrp + 2 * D + j);
      float4 w3 = *(const float4*)(Wrp + 3 * D + j);
      float r0 = fmaxf(b.x + d0 * w0.x + d1 * w1.x + d2 * w2.x + d3 * w3.x, 0.f);
      float r1 = fmaxf(b.y + d0 * w0.y + d1 * w1.y + d2 * w2.y + d3 * w3.y, 0.f);
      float r2 = fmaxf(b.z + d0 * w0.z + d1 * w1.z + d2 * w2.z + d3 * w3.z, 0.f);
      float r3 = fmaxf(b.w + d0 * w0.w + d1 * w1.w + d2 * w2.w + d3 * w3.w, 0.f);
      *(uint2*)&Ybuf[e * 136 + j] = make_uint2(pk2(r0, r1), pk2(r2, r3));
    }
  }
  __syncthreads();  // Wbuf[0], Ybuf (relpose), wl all ready

  // ---- GEMM1: K=256 (chunks 0..3 cfeat-from-global, 4..7 relpose-from-LDS)
  f32x4 acc1[4][4];
#pragma unroll
  for (int m = 0; m < 4; ++m)
#pragma unroll
    for (int n = 0; n < 4; ++n) acc1[m][n] = (f32x4){0.f, 0.f, 0.f, 0.f};

  for (int kc = 0; kc < 8; ++kc) {
    const int nb = kc & 1;
    stage(kc + 1, nb ^ 1);
    bf16x8 a[4];
    if (kc < 4) {
#pragma unroll
      for (int m = 0; m < 4; ++m) {
        const float* src = cfeat + (size_t)hl[m] * D + kc * 32 + g * 8;
        float4 f0 = *(const float4*)src;
        float4 f1 = *(const float4*)(src + 4);
        union { uint4 u; bf16x8 v; } cv;
        cv.u.x = pk2(f0.x, f0.y); cv.u.y = pk2(f0.z, f0.w);
        cv.u.z = pk2(f1.x, f1.y); cv.u.w = pk2(f1.z, f1.w);
        a[m] = cv.v;
      }
    } else {
#pragma unroll
      for (int m = 0; m < 4; ++m)
        a[m] = *(const bf16x8*)
            &Ybuf[(wm * 64 + m * 16 + s) * 136 + (kc - 4) * 32 + g * 8];
    }
#pragma unroll
    for (int n = 0; n < 4; ++n) {
      bf16x8 b = *(const bf16x8*)
          &Wbuf[nb][(g * 128 + wn * 64 + n * 16 + s) * 8];
#pragma unroll
      for (int m = 0; m < 4; ++m)
        acc1[m][n] =
            __builtin_amdgcn_mfma_f32_16x16x32_bf16(a[m], b, acc1[m][n], 0, 0, 0);
    }
    __syncthreads();
  }

  // ---- GroupNorm(128) + relu -> Ybuf (bf16) ----
#pragma unroll
  for (int m = 0; m < 4; ++m) {
#pragma unroll
    for (int reg = 0; reg < 4; ++reg) {
      float p1 = acc1[m][0][reg] + acc1[m][1][reg] + acc1[m][2][reg] +
                 acc1[m][3][reg];
      float p2 = acc1[m][0][reg] * acc1[m][0][reg] +
                 acc1[m][1][reg] * acc1[m][1][reg] +
                 acc1[m][2][reg] * acc1[m][2][reg] +
                 acc1[m][3][reg] * acc1[m][3][reg];
#pragma unroll
      for (int msk = 1; msk < 16; msk <<= 1) {
        p1 += __shfl_xor(p1, msk, 64);
        p2 += __shfl_xor(p2, msk, 64);
      }
      if (s == 0) {
        const int row = wm * 64 + m * 16 + g * 4 + reg;
        *(float2*)&gnbuf[wn][row][0] = make_float2(p1, p2);
      }
    }
  }
  __syncthreads();
  {
    float gcl[4], bcl[4];
#pragma unroll
    for (int n = 0; n < 4; ++n) {
      gcl[n] = gc1[wn * 64 + n * 16 + s];
      bcl[n] = bc1[wn * 64 + n * 16 + s];
    }
#pragma unroll
    for (int m = 0; m < 4; ++m) {
#pragma unroll
      for (int reg = 0; reg < 4; ++reg) {
        const int row = wm * 64 + m * 16 + g * 4 + reg;
        float2 q0 = *(const float2*)&gnbuf[0][row][0];
        float2 q1 = *(const float2*)&gnbuf[1][row][0];
        const float mean = (q0.x + q1.x) * (1.f / 128.f);
        const float var = (q0.y + q1.y) * (1.f / 128.f) - mean * mean;
        const float rstd = rsqrtf(var + EPSV);
#pragma unroll
        for (int n = 0; n < 4; ++n) {
          float y = (acc1[m][n][reg] - mean) * rstd * gcl[n] + bcl[n];
          Ybuf[row * 136 + wn * 64 + n * 16 + s] = f2bf(fmaxf(y, 0.f));
        }
      }
    }
  }
  __syncthreads();

  // ---- GEMM2: K=128 (W chunks 8..11), A = Ybuf ----
  f32x4 acc2[4][4];
#pragma unroll
  for (int m = 0; m < 4; ++m)
#pragma unroll
    for (int n = 0; n < 4; ++n) acc2[m][n] = (f32x4){0.f, 0.f, 0.f, 0.f};

  for (int kc = 0; kc < 4; ++kc) {
    const int c = 8 + kc;
    const int nb = c & 1;
    if (c < 11) stage(c + 1, nb ^ 1);
    bf16x8 a[4];
#pragma unroll
    for (int m = 0; m < 4; ++m)
      a[m] = *(const bf16x8*)
          &Ybuf[(wm * 64 + m * 16 + s) * 136 + kc * 32 + g * 8];
#pragma unroll
    for (int n = 0; n < 4; ++n) {
      bf16x8 b = *(const bf16x8*)
          &Wbuf[nb][(g * 128 + wn * 64 + n * 16 + s) * 8];
#pragma unroll
      for (int m = 0; m < 4; ++m)
        acc2[m][n] =
            __builtin_amdgcn_mfma_f32_16x16x32_bf16(a[m], b, acc2[m][n], 0, 0, 0);
    }
    if (kc < 3) __syncthreads();
  }

  // ---- scatter-add ----
#pragma unroll
  for (int m = 0; m < 4; ++m) {
#pragma unroll
    for (int reg = 0; reg < 4; ++reg) {
      const int rl = wm * 64 + m * 16 + g * 4 + reg;
      if (e0 + rl < E) {
        const int w = wl[rl];
        float* base = acc + (size_t)w * D + wn * 64 + s;
#pragma unroll
        for (int n = 0; n < 4; ++n)
          unsafeAtomicAdd(base + n * 16, acc2[m][n][reg]);
      }
    }
  }
}

// ---------------------------------------------------------------------------
__device__ __forceinline__ void reduce16(float& a, float& b) {
#pragma unroll
  for (int w = 1; w < 16; w <<= 1) {
    a += __shfl_xor(a, w, 64);
    b += __shfl_xor(b, w, 64);
  }
}

// ---------------------------------------------------------------------------
// k_input v2: 64 rows/block, 4 rows/thread (W LDS-reads amortized 4x).
__global__ __launch_bounds__(256, 2) void k_input(
    const float* __restrict__ tfeat, const float* __restrict__ Wi,
    float* __restrict__ acc, int N) {
  __shared__ float Wbuf[64][132];
  __shared__ float xt[64][132];
  const int t = threadIdx.x;
  const int r = t >> 4, s = t & 15, j0 = s * 8;
  const int row0 = blockIdx.x * 64;

  for (int idx = t; idx < 64 * 32; idx += 256) {
    int rr = idx >> 5, c4 = idx & 31;
    int grow = row0 + rr;
    float4 v = make_float4(0.f, 0.f, 0.f, 0.f);
    if (grow < N) v = *(const float4*)(tfeat + (size_t)grow * D + c4 * 4);
    *(float4*)&xt[rr][c4 * 4] = v;
  }

  float a[4][8] = {};
  for (int kc = 0; kc < 2; ++kc) {
    __syncthreads();
    for (int idx = t; idx < 64 * 32; idx += 256) {
      int kk = idx >> 5, c4 = idx & 31;
      *(float4*)&Wbuf[kk][c4 * 4] =
          *(const float4*)(Wi + (size_t)(kc * 64 + kk) * D + c4 * 4);
    }
    __syncthreads();
#pragma unroll 4
    for (int kk = 0; kk < 64; ++kk) {
      float4 w0 = *(const float4*)&Wbuf[kk][j0];
      float4 w1 = *(const float4*)&Wbuf[kk][j0 + 4];
#pragma unroll
      for (int i = 0; i < 4; ++i) {
        float xv = xt[r + 16 * i][kc * 64 + kk];
        a[i][0] += xv * w0.x; a[i][1] += xv * w0.y;
        a[i][2] += xv * w0.z; a[i][3] += xv * w0.w;
        a[i][4] += xv * w1.x; a[i][5] += xv * w1.y;
        a[i][6] += xv * w1.z; a[i][7] += xv * w1.w;
      }
    }
  }
#pragma unroll
  for (int i = 0; i < 4; ++i) {
    int row = row0 + r + 16 * i;
    if (row < N) {
      *(float4*)(acc + (size_t)row * D + j0) =
          make_float4(a[i][0], a[i][1], a[i][2], a[i][3]);
      *(float4*)(acc + (size_t)row * D + j0 + 4) =
          make_float4(a[i][4], a[i][5], a[i][6], a[i][7]);
    }
  }
}

// ---------------------------------------------------------------------------
// k_node v2: 64 rows/block, 4 rows/thread; xt buffer reused for yt.
__global__ __launch_bounds__(256, 2) void k_node(
    const float* __restrict__ tfeat,
    const float* __restrict__ gn, const float* __restrict__ bn,
    const float* __restrict__ Wm1, const float* __restrict__ gm1,
    const float* __restrict__ bm1,
    const float* __restrict__ Wm2, const float* __restrict__ gm2,
    const float* __restrict__ bm2,
    float* __restrict__ acc, int N) {
  __shared__ float Wbuf[64][132];
  __shared__ float xt[64][132];
  const int t = threadIdx.x;
  const int r = t >> 4, s = t & 15, j0 = s * 8;
  const int row0 = blockIdx.x * 64;

  auto stageW = [&](const float* W, int kc) {
    for (int idx = t; idx < 64 * 32; idx += 256) {
      int kk = idx >> 5, c4 = idx & 31;
      *(float4*)&Wbuf[kk][c4 * 4] =
          *(const float4*)(W + (size_t)(kc * 64 + kk) * D + c4 * 4);
    }
  };
  auto gemm = [&](float a[4][8], int kc) {
#pragma unroll 4
    for (int kk = 0; kk < 64; ++kk) {
      float4 w0 = *(const float4*)&Wbuf[kk][j0];
      float4 w1 = *(const float4*)&Wbuf[kk][j0 + 4];
#pragma unroll
      for (int i = 0; i < 4; ++i) {
        float xv = xt[r + 16 * i][kc * 64 + kk];
        a[i][0] += xv * w0.x; a[i][1] += xv * w0.y;
        a[i][2] += xv * w0.z; a[i][3] += xv * w0.w;
        a[i][4] += xv * w1.x; a[i][5] += xv * w1.y;
        a[i][6] += xv * w1.z; a[i][7] += xv * w1.w;
      }
    }
  };

  // Stage 1: GN(acc rows) + relu -> xt
  {
    float gv[8], bv[8];
#pragma unroll
    for (int m = 0; m < 8; ++m) { gv[m] = gn[j0 + m]; bv[m] = bn[j0 + m]; }
#pragma unroll
    for (int i = 0; i < 4; ++i) {
      int row = row0 + r + 16 * i;
      float v[8] = {};
      if (row < N) {
        float4 v0 = *(const float4*)(acc + (size_t)row * D + j0);
        float4 v1 = *(const float4*)(acc + (size_t)row * D + j0 + 4);
        v[0] = v0.x; v[1] = v0.y; v[2] = v0.z; v[3] = v0.w;
        v[4] = v1.x; v[5] = v1.y; v[6] = v1.z; v[7] = v1.w;
      }
      float s1 = 0.f, s2 = 0.f;
#pragma unroll
      for (int m = 0; m < 8; ++m) { s1 += v[m]; s2 += v[m] * v[m]; }
      reduce16(s1, s2);
      float mean = s1 * (1.f / 128.f);
      float var = s2 * (1.f / 128.f) - mean * mean;
      float rstd = rsqrtf(var + EPSV);
#pragma unroll
      for (int m = 0; m < 8; ++m)
        xt[r + 16 * i][j0 + m] = fmaxf((v[m] - mean) * rstd * gv[m] + bv[m], 0.f);
    }
  }

  // Stage 2: a = xt @ Wm1; GN + relu -> xt
  float a[4][8] = {};
  for (int kc = 0; kc < 2; ++kc) {
    __syncthreads();
    stageW(Wm1, kc);
    __syncthreads();
    gemm(a, kc);
  }
  __syncthreads();  // all reads of xt done before overwrite
  {
    float gv[8], bv[8];
#pragma unroll
    for (int m = 0; m < 8; ++m) { gv[m] = gm1[j0 + m]; bv[m] = bm1[j0 + m]; }
#pragma unroll
    for (int i = 0; i < 4; ++i) {
      float s1 = 0.f, s2 = 0.f;
#pragma unroll
      for (int m = 0; m < 8; ++m) { s1 += a[i][m]; s2 += a[i][m] * a[i][m]; }
      reduce16(s1, s2);
      float mean = s1 * (1.f / 128.f);
      float var = s2 * (1.f / 128.f) - mean * mean;
      float rstd = rsqrtf(var + EPSV);
#pragma unroll
      for (int m = 0; m < 8; ++m)
        xt[r + 16 * i][j0 + m] =
            fmaxf((a[i][m] - mean) * rstd * gv[m] + bv[m], 0.f);
    }
  }

  // Stage 3: a2 = xt @ Wm2; GN; residual + relu -> acc
  float a2[4][8] = {};
  for (int kc = 0; kc < 2; ++kc) {
    __syncthreads();
    stageW(Wm2, kc);
    __syncthreads();
    gemm(a2, kc);
  }
  {
    float gv[8], bv[8];
#pragma unroll
    for (int m = 0; m < 8; ++m) { gv[m] = gm2[j0 + m]; bv[m] = bm2[j0 + m]; }
#pragma unroll
    for (int i = 0; i < 4; ++i) {
      int row = row0 + r + 16 * i;
      float s1 = 0.f, s2 = 0.f;
#pragma unroll
      for (int m = 0; m < 8; ++m) { s1 += a2[i][m]; s2 += a2[i][m] * a2[i][m]; }
      reduce16(s1, s2);
      float mean = s1 * (1.f / 128.f);
      float var = s2 * (1.f / 128.f) - mean * mean;
      float rstd = rsqrtf(var + EPSV);
      if (row < N) {
        float o[8];
#pragma unroll
        for (int m = 0; m < 8; ++m) {
          float x = (a2[i][m] - mean) * rstd * gv[m] + bv[m];
          o[m] = fmaxf(x + tfeat[(size_t)row * D + j0 + m], 0.f);
        }
        *(float4*)(acc + (size_t)row * D + j0) =
            make_float4(o[0], o[1], o[2], o[3]);
        *(float4*)(acc + (size_t)row * D + j0 + 4) =
            make_float4(o[4], o[5], o[6], o[7]);
      }
    }
  }
}

// ---------------------------------------------------------------------------
extern "C" void kernel_launch(void* const* d_in, const int* in_sizes, int n_in,
                              void* d_out, int out_size, void* d_ws,
                              size_t ws_size, hipStream_t stream) {
  const float* cfeat = (const float*)d_in[0];
  const float* tfeat = (const float*)d_in[1];
  const float* cpose = (const float*)d_in[2];
  const float* tpose = (const float*)d_in[3];
  const float* Wi    = (const float*)d_in[4];
  const float* Wrp   = (const float*)d_in[5];
  const float* brp   = (const float*)d_in[6];
  const float* Wc1   = (const float*)d_in[7];
  const float* gc1   = (const float*)d_in[8];
  const float* bc1   = (const float*)d_in[9];
  const float* Wc2   = (const float*)d_in[10];
  const float* gn    = (const float*)d_in[11];
  const float* bn    = (const float*)d_in[12];
  const float* Wm1   = (const float*)d_in[13];
  const float* gm1   = (const float*)d_in[14];
  const float* bm1   = (const float*)d_in[15];
  const float* Wm2   = (const float*)d_in[16];
  const float* gm2   = (const float*)d_in[17];
  const float* bm2   = (const float*)d_in[18];
  const int* hi      = (const int*)d_in[19];
  const int* wi      = (const int*)d_in[20];

  const int N = in_sizes[1] / D;   // 40000 targets
  const int E = in_sizes[19];      // 640000 edges
  float* out = (float*)d_out;      // f32 accumulator == output

  ushort* WT1 = (ushort*)d_ws;     // 128x256 bf16 (Wc1^T)
  ushort* WT2 = WT1 + 128 * 256;   // 128x128 bf16 (Wc2^T)

  const int nbN = (N + 63) / 64;
  const int nbE = (E + 127) / 128;

  k_cvt<<<192, 256, 0, stream>>>(Wc1, Wc2, WT1, WT2);
  k_input<<<nbN, 256, 0, stream>>>(tfeat, Wi, out, N);
  k_edge<<<nbE, 256, 0, stream>>>(cfeat, cpose, tpose, Wrp, brp, gc1, bc1,
                                  WT1, WT2, hi, wi, out, E);
  k_node<<<nbN, 256, 0, stream>>>(tfeat, gn, bn, Wm1, gm1, bm1, Wm2, gm2, bm2,
                                  out, N);
}